// Round 6
// baseline (719.728 us; speedup 1.0000x reference)
//
#include <hip/hip_runtime.h>
#include <cstdint>
#include <cstddef>

// CausalSelfAttention MI355X (gfx950). fp32 I/O, bf16 MFMA compute, fp32 accum.
// B=2, T=2048, C=1024, H=16, Dh=64.
// [cast f32->bf16] -> [gemm qkv (global_load_lds), V stored transposed]
// -> [rmsnorm+rope in-place] -> [flash attention: S^T, static-max softmax,
//     lgkm-only barriers + depth-2 reg prefetch] -> [gemm proj -> f32 out]

typedef short bf16x8 __attribute__((ext_vector_type(8)));
typedef float floatx4 __attribute__((ext_vector_type(4)));
typedef unsigned short ushortx8 __attribute__((ext_vector_type(8)));
typedef unsigned int uintx2 __attribute__((ext_vector_type(2)));

#define DEVI __device__ __forceinline__

DEVI float bf2f(unsigned short u) {
    unsigned int x = ((unsigned int)u) << 16;
    return __builtin_bit_cast(float, x);
}
DEVI unsigned short f2bf(float f) {
    unsigned int u = __builtin_bit_cast(unsigned int, f);
    u += 0x7fffu + ((u >> 16) & 1u);   // RNE; finite values only
    return (unsigned short)(u >> 16);
}
// pack 2 fp32 -> 2 bf16 (round-half-up; inputs >= 0 here) in one dword
DEVI unsigned int pkbf2(float a, float b) {
    unsigned int ua = __builtin_bit_cast(unsigned int, a) + 0x8000u;
    unsigned int ub = __builtin_bit_cast(unsigned int, b) + 0x8000u;
    return __builtin_amdgcn_perm(ub, ua, 0x07060302);  // [ua.hi16 | ub.hi16]
}
// workgroup barrier WITHOUT vmcnt drain (LDS ordering only). Global loads in
// flight to registers survive the barrier; compiler waits vmcnt at their use.
DEVI void barrier_lgkm() {
    asm volatile("s_waitcnt lgkmcnt(0)\ns_barrier" ::: "memory");
}

// async global->LDS, 16B per lane; LDS dest = wave-uniform base + lane*16.
DEVI void glds16(const unsigned short* g, unsigned short* l) {
    __builtin_amdgcn_global_load_lds(
        (const __attribute__((address_space(1))) unsigned int*)g,
        (__attribute__((address_space(3))) unsigned int*)l, 16, 0, 0);
}

DEVI void cast8(unsigned short* dst, const float* src) {
    floatx4 a = *(const floatx4*)src;
    floatx4 b = *(const floatx4*)(src + 4);
    ushortx8 o;
    o[0] = f2bf(a[0]); o[1] = f2bf(a[1]); o[2] = f2bf(a[2]); o[3] = f2bf(a[3]);
    o[4] = f2bf(b[0]); o[5] = f2bf(b[1]); o[6] = f2bf(b[2]); o[7] = f2bf(b[3]);
    *(ushortx8*)dst = o;
}

// ---------------------------------------------------------------------------
__global__ __launch_bounds__(256)
void cast_inputs(const float* __restrict__ x, const float* __restrict__ wa,
                 const float* __restrict__ wp,
                 unsigned short* __restrict__ xb, unsigned short* __restrict__ wab,
                 unsigned short* __restrict__ wpb)
{
    size_t g = (size_t)blockIdx.x * 256 + threadIdx.x;
    size_t stride = (size_t)gridDim.x * 256;
    for (size_t i = g; i < (4194304 / 8); i += stride) cast8(xb  + i * 8, x  + i * 8);
    for (size_t i = g; i < (3145728 / 8); i += stride) cast8(wab + i * 8, wa + i * 8);
    for (size_t i = g; i < (1048576 / 8); i += stride) cast8(wpb + i * 8, wp + i * 8);
}

// ---------------------------------------------------------------------------
// C[M,N] = A[M,K] @ B[N,K]^T, bf16 in, fp32 accum. m97 structure: 128x128
// tile, BK=32, global_load_lds width=16 into UNPADDED LDS (row = 64B).
// QKV_SPLIT: col<2048 -> Cqk[row*2048+col] bf16; col>=2048 -> Vt[bh*64+d][t].
// else: Cf[row*N+col] fp32.
// ---------------------------------------------------------------------------
template <bool QKV_SPLIT>
__global__ __launch_bounds__(256)
void gemm_bt(const unsigned short* __restrict__ A, const unsigned short* __restrict__ B,
             unsigned short* __restrict__ Cqk, float* __restrict__ Cf,
             unsigned short* __restrict__ Vt, int M, int N, int K)
{
    __shared__ __align__(16) unsigned short As[128 * 32];
    __shared__ __align__(16) unsigned short Bs[128 * 32];

    const int tid  = threadIdx.x;
    const int lane = tid & 63;
    const int w    = tid >> 6;
    const int wm   = w >> 1, wn = w & 1;
    const int quad = lane >> 4;
    const int lm   = lane & 15;
    const int m0 = blockIdx.y * 128;
    const int n0 = blockIdx.x * 128;
    const int sr = lane >> 2;          // staging row within 16-row group
    const int sc = (lane & 3) * 8;     // staging col (8 shorts = 16B)

    floatx4 acc[4][4] = {};

    for (int k0 = 0; k0 < K; k0 += 32) {
        __syncthreads();               // WAR: everyone done reading LDS
        #pragma unroll
        for (int i = 0; i < 2; ++i) {
            int r = w * 32 + i * 16;   // wave-uniform group base row
            glds16(&A[(size_t)(m0 + r + sr) * K + k0 + sc], &As[r * 32]);
            glds16(&B[(size_t)(n0 + r + sr) * K + k0 + sc], &Bs[r * 32]);
        }
        __syncthreads();               // vmcnt(0) drained before barrier

        bf16x8 a[4];
        #pragma unroll
        for (int i = 0; i < 4; ++i)
            a[i] = *(const bf16x8*)&As[(wm * 64 + i * 16 + lm) * 32 + quad * 8];
        #pragma unroll
        for (int j = 0; j < 4; ++j) {
            bf16x8 b = *(const bf16x8*)&Bs[(wn * 64 + j * 16 + lm) * 32 + quad * 8];
            #pragma unroll
            for (int i = 0; i < 4; ++i)
                acc[i][j] = __builtin_amdgcn_mfma_f32_16x16x32_bf16(a[i], b, acc[i][j], 0, 0, 0);
        }
    }

    // C/D layout: col = lane&15, row = quad*4 + reg
    #pragma unroll
    for (int i = 0; i < 4; ++i) {
        #pragma unroll
        for (int j = 0; j < 4; ++j) {
            int col = n0 + wn * 64 + j * 16 + lm;
            #pragma unroll
            for (int r = 0; r < 4; ++r) {
                int row = m0 + wm * 64 + i * 16 + quad * 4 + r;
                if constexpr (QKV_SPLIT) {
                    unsigned short v = f2bf(acc[i][j][r]);
                    if (col < 2048) {
                        Cqk[(size_t)row * 2048 + col] = v;           // q,k thirds
                    } else {
                        int bq = row >> 11, t = row & 2047;          // V -> Vt[bh*64+d][t]
                        Vt[((size_t)(bq * 1024 + (col - 2048))) * 2048 + t] = v;
                    }
                } else {
                    Cf[(size_t)row * N + col] = acc[i][j][r];
                }
            }
        }
    }
}

// ---------------------------------------------------------------------------
// RMSNorm (Dh=64, eps=f32 eps) + rotary, IN PLACE on qk [B,T,2C] bf16.
// ---------------------------------------------------------------------------
__global__ __launch_bounds__(256)
void rmsnorm_rope(unsigned short* __restrict__ qk)
{
    int gw   = (blockIdx.x * 256 + threadIdx.x) >> 6;
    int lane = threadIdx.x & 63;
    int h = gw & 15;
    int t = (gw >> 4) & 2047;
    int b = gw >> 15;

    size_t base = ((size_t)(b * 2048 + t)) * 2048 + h * 64 + lane;
    float q = bf2f(qk[base]);
    float k = bf2f(qk[base + 1024]);

    float sq = q * q, sk = k * k;
    #pragma unroll
    for (int off = 32; off >= 1; off >>= 1) {
        sq += __shfl_xor(sq, off, 64);
        sk += __shfl_xor(sk, off, 64);
    }
    const float eps = 1.1920929e-07f;
    q *= rsqrtf(sq * (1.0f / 64.0f) + eps);
    k *= rsqrtf(sk * (1.0f / 64.0f) + eps);

    int i = lane & 31;
    float ang = (float)t * expf(-(float)i * 0.28782313662425572f);  // ln(1e4)/32
    float c = cosf(ang), s = sinf(ang);
    float qp = __shfl_xor(q, 32, 64);
    float kp = __shfl_xor(k, 32, 64);
    float sgn = (lane < 32) ? -1.0f : 1.0f;
    float qo = q * c + sgn * qp * s;
    float ko = k * c + sgn * kp * s;

    qk[base]        = f2bf(qo);
    qk[base + 1024] = f2bf(ko);
}

// ---------------------------------------------------------------------------
// Flash attention, static-max softmax (RMSNorm => |s|<=8 => p=exp(s-8), no
// rescale, masked entries exactly 0). S^T via mfma(A=K, B=Q): lane holds one
// q-row, key-contiguous P -> packed b64 P writes. NEW this round:
//  - barrier_lgkm(): barriers drain lgkm only; global prefetch stays in flight
//  - depth-2 ping-pong register prefetch (tile kt+2 issued at kt)
//  - v_perm-packed P conversion (round-half-up)
// ---------------------------------------------------------------------------
__global__ __launch_bounds__(256)
void attention(const unsigned short* __restrict__ qk,
               const unsigned short* __restrict__ Vt,
               unsigned short* __restrict__ Y)
{
    constexpr int LD = 72;
    __shared__ __align__(16) unsigned short QPs[64 * LD];  // Q stage, then P
    __shared__ __align__(16) unsigned short Ks [64 * LD];
    __shared__ __align__(16) unsigned short Vs [64 * LD];  // rows=d, cols=key

    const int tid  = threadIdx.x;
    const int lane = tid & 63;
    const int w    = tid >> 6;
    const int quad = lane >> 4;
    const int lm   = lane & 15;

    const int bh = blockIdx.x;
    const int qt = 31 - blockIdx.y;      // longest first
    const int b  = bh >> 4, h = bh & 15;
    const int q0 = qt * 64;
    const int qrow = q0 + w * 16 + lm;   // this lane's q-row (S^T layout)

    // per-thread staging coords (row = key idx or d idx, col = 8-elem chunk)
    const int pr0 = tid >> 3,        pc = (tid & 7) * 8;    // chunk 0: rows 0..31
    const int pr1 = (256 + tid) >> 3;                       // chunk 1: rows 32..63
    const unsigned short* kbase = qk + (size_t)b * 2048 * 2048 + 1024 + h * 64;
    const unsigned short* vbase = Vt + (size_t)bh * 64 * 2048;

    // stage Q tile
    #pragma unroll
    for (int i = 0; i < 2; ++i) {
        int c = i * 256 + tid, row = c >> 3, col = (c & 7) * 8;
        *(ushortx8*)&QPs[row * LD + col] =
            *(const ushortx8*)&qk[((size_t)(b * 2048 + q0 + row)) * 2048 + h * 64 + col];
    }

    // depth-2 prefetch: tiles 0 and 1 (clamped)
    ushortx8 kreg[2][2], vreg[2][2];
    {
        kreg[0][0] = *(const ushortx8*)&kbase[(size_t)pr0 * 2048 + pc];
        kreg[0][1] = *(const ushortx8*)&kbase[(size_t)pr1 * 2048 + pc];
        vreg[0][0] = *(const ushortx8*)&vbase[(size_t)pr0 * 2048 + pc];
        vreg[0][1] = *(const ushortx8*)&vbase[(size_t)pr1 * 2048 + pc];
        int t1 = (qt >= 1) ? 64 : 0;
        kreg[1][0] = *(const ushortx8*)&kbase[(size_t)(t1 + pr0) * 2048 + pc];
        kreg[1][1] = *(const ushortx8*)&kbase[(size_t)(t1 + pr1) * 2048 + pc];
        vreg[1][0] = *(const ushortx8*)&vbase[(size_t)pr0 * 2048 + t1 + pc];
        vreg[1][1] = *(const ushortx8*)&vbase[(size_t)pr1 * 2048 + t1 + pc];
    }

    floatx4 o[4] = {};
    float lsum = 0.0f;
    bf16x8 qf[2];
    const float c1 = 0.125f * 1.44269504f;   // scale * log2(e)
    const float c2 = 8.0f   * 1.44269504f;   // static max 8

    for (int kt = 0; kt <= qt; ++kt) {
        const int k0 = kt * 64;
        const int cur = kt & 1;
        barrier_lgkm();                      // waves done reading prev tile (LDS only)
        *(ushortx8*)&Ks[pr0 * LD + pc] = kreg[cur][0];
        *(ushortx8*)&Ks[pr1 * LD + pc] = kreg[cur][1];
        *(ushortx8*)&Vs[pr0 * LD + pc] = vreg[cur][0];
        *(ushortx8*)&Vs[pr1 * LD + pc] = vreg[cur][1];
        barrier_lgkm();                      // staging visible

        if (kt == 0) {                       // hoist Q frags (after barrier: visible)
            #pragma unroll
            for (int kk = 0; kk < 2; ++kk)
                qf[kk] = *(const bf16x8*)&QPs[(w * 16 + lm) * LD + kk * 32 + quad * 8];
        }
        if (kt + 2 <= qt) {                  // refill consumed slot with tile kt+2
            const int kn = k0 + 128;
            kreg[cur][0] = *(const ushortx8*)&kbase[(size_t)(kn + pr0) * 2048 + pc];
            kreg[cur][1] = *(const ushortx8*)&kbase[(size_t)(kn + pr1) * 2048 + pc];
            vreg[cur][0] = *(const ushortx8*)&vbase[(size_t)pr0 * 2048 + kn + pc];
            vreg[cur][1] = *(const ushortx8*)&vbase[(size_t)pr1 * 2048 + kn + pc];
        }

        // S^T: lane(quad,lm): q = qrow, key = k0 + j*16 + quad*4 + r
        floatx4 sa[4] = {};
        #pragma unroll
        for (int kk = 0; kk < 2; ++kk) {
            #pragma unroll
            for (int j = 0; j < 4; ++j) {
                bf16x8 kf = *(const bf16x8*)&Ks[(j * 16 + lm) * LD + kk * 32 + quad * 8];
                sa[j] = __builtin_amdgcn_mfma_f32_16x16x32_bf16(kf, qf[kk], sa[j], 0, 0, 0);
            }
        }

        // p = exp2(s*c1 - c2); mask; perm-pack 4 key-contiguous bf16 -> b64
        const bool dg = (kt == qt);
        #pragma unroll
        for (int j = 0; j < 4; ++j) {
            int kb = k0 + j * 16 + quad * 4;
            float p0 = exp2f(sa[j][0] * c1 - c2);
            float p1 = exp2f(sa[j][1] * c1 - c2);
            float p2 = exp2f(sa[j][2] * c1 - c2);
            float p3 = exp2f(sa[j][3] * c1 - c2);
            if (dg) {
                if (kb + 0 > qrow) p0 = 0.0f;
                if (kb + 1 > qrow) p1 = 0.0f;
                if (kb + 2 > qrow) p2 = 0.0f;
                if (kb + 3 > qrow) p3 = 0.0f;
            }
            lsum += (p0 + p1) + (p2 + p3);
            uintx2 pk;
            pk[0] = pkbf2(p0, p1);
            pk[1] = pkbf2(p2, p3);
            *(uintx2*)&QPs[(w * 16 + lm) * LD + j * 16 + quad * 4] = pk;
        }

        // O += P V: A = P (own strip, same-wave LDS RAW), B = V^T
        #pragma unroll
        for (int kk = 0; kk < 2; ++kk) {
            bf16x8 pf = *(const bf16x8*)&QPs[(w * 16 + lm) * LD + kk * 32 + quad * 8];
            #pragma unroll
            for (int j = 0; j < 4; ++j) {
                bf16x8 vf = *(const bf16x8*)&Vs[(j * 16 + lm) * LD + kk * 32 + quad * 8];
                o[j] = __builtin_amdgcn_mfma_f32_16x16x32_bf16(pf, vf, o[j], 0, 0, 0);
            }
        }
    }

    // row-sum at lane lm (dup over quads after reduce) -> C-layout rows
    float lt = lsum;
    lt += __shfl_xor(lt, 16, 64);
    lt += __shfl_xor(lt, 32, 64);
    float rv = 1.0f / lt;
    float rinv[4];
    #pragma unroll
    for (int r = 0; r < 4; ++r)
        rinv[r] = __shfl(rv, (quad << 4) + quad * 4 + r, 64);

    #pragma unroll
    for (int j = 0; j < 4; ++j) {
        int colg = h * 64 + j * 16 + lm;
        #pragma unroll
        for (int r = 0; r < 4; ++r) {
            int rowg = q0 + w * 16 + quad * 4 + r;
            Y[((size_t)(b * 2048 + rowg)) * 1024 + colg] = f2bf(o[j][r] * rinv[r]);
        }
    }
}

// ---------------------------------------------------------------------------
extern "C" void kernel_launch(void* const* d_in, const int* in_sizes, int n_in,
                              void* d_out, int out_size, void* d_ws, size_t ws_size,
                              hipStream_t stream)
{
    const float* x      = (const float*)d_in[0];   // [2,2048,1024] fp32
    const float* w_attn = (const float*)d_in[1];   // [3072,1024] fp32
    const float* w_proj = (const float*)d_in[2];   // [1024,1024] fp32
    float* out = (float*)d_out;                    // [2,2048,1024] fp32

    // ws: qk 16.8MB | Vt 8.4MB | y 8.4MB | wpb 2.1MB  (35.7 MB total)
    unsigned short* qkbuf = (unsigned short*)d_ws;
    unsigned short* Vtb   = qkbuf + (size_t)4096 * 2048;
    unsigned short* y     = Vtb   + (size_t)32 * 64 * 2048;
    unsigned short* wpb   = y     + (size_t)4096 * 1024;
    // d_out doubles as pre-cast scratch for xb/wab (dead before proj writes):
    unsigned short* xb  = (unsigned short*)d_out;             // 8.4MB
    unsigned short* wab = xb + (size_t)4096 * 1024;           // 6.3MB

    dim3 blk(256);
    cast_inputs<<<dim3(1024), blk, 0, stream>>>(x, w_attn, w_proj, xb, wab, wpb);
    gemm_bt<true>
        <<<dim3(24, 32), blk, 0, stream>>>(xb, wab, qkbuf, nullptr, Vtb, 4096, 3072, 1024);
    rmsnorm_rope<<<dim3(16384), blk, 0, stream>>>(qkbuf);
    attention<<<dim3(32, 32), blk, 0, stream>>>(qkbuf, Vtb, y);
    gemm_bt<false>
        <<<dim3(8, 32), blk, 0, stream>>>(y, wpb, nullptr, out, nullptr, 4096, 1024, 1024);
}

// Round 7
// 209.488 us; speedup vs baseline: 3.4357x; 3.4357x over previous
//
#include <hip/hip_runtime.h>
#include <cstdint>
#include <cstddef>

// CausalSelfAttention MI355X (gfx950). fp32 I/O, bf16 MFMA compute, fp32 accum.
// B=2, T=2048, C=1024, H=16, Dh=64.
// [cast f32->bf16] -> [gemm qkv (global_load_lds), V stored transposed]
// -> [rmsnorm+rope in-place] -> [flash attention: S^T, static-max softmax,
//     q-tile PAIRING for perfect balance] -> [gemm proj BN=64 -> f32 out]
// Round 6 failed (10x): runtime-indexed reg arrays + asm barrier => VALU
// explosion. All three round-6 mechanisms reverted; round-5 inner loop kept.

typedef short bf16x8 __attribute__((ext_vector_type(8)));
typedef float floatx4 __attribute__((ext_vector_type(4)));
typedef unsigned short ushortx8 __attribute__((ext_vector_type(8)));
typedef unsigned short ushortx4 __attribute__((ext_vector_type(4)));

#define DEVI __device__ __forceinline__

DEVI float bf2f(unsigned short u) {
    unsigned int x = ((unsigned int)u) << 16;
    return __builtin_bit_cast(float, x);
}
DEVI unsigned short f2bf(float f) {
    unsigned int u = __builtin_bit_cast(unsigned int, f);
    u += 0x7fffu + ((u >> 16) & 1u);   // RNE; finite values only
    return (unsigned short)(u >> 16);
}

// async global->LDS, 16B per lane; LDS dest = wave-uniform base + lane*16.
DEVI void glds16(const unsigned short* g, unsigned short* l) {
    __builtin_amdgcn_global_load_lds(
        (const __attribute__((address_space(1))) unsigned int*)g,
        (__attribute__((address_space(3))) unsigned int*)l, 16, 0, 0);
}

DEVI void cast8(unsigned short* dst, const float* src) {
    floatx4 a = *(const floatx4*)src;
    floatx4 b = *(const floatx4*)(src + 4);
    ushortx8 o;
    o[0] = f2bf(a[0]); o[1] = f2bf(a[1]); o[2] = f2bf(a[2]); o[3] = f2bf(a[3]);
    o[4] = f2bf(b[0]); o[5] = f2bf(b[1]); o[6] = f2bf(b[2]); o[7] = f2bf(b[3]);
    *(ushortx8*)dst = o;
}

// ---------------------------------------------------------------------------
__global__ __launch_bounds__(256)
void cast_inputs(const float* __restrict__ x, const float* __restrict__ wa,
                 const float* __restrict__ wp,
                 unsigned short* __restrict__ xb, unsigned short* __restrict__ wab,
                 unsigned short* __restrict__ wpb)
{
    size_t g = (size_t)blockIdx.x * 256 + threadIdx.x;
    size_t stride = (size_t)gridDim.x * 256;
    for (size_t i = g; i < (4194304 / 8); i += stride) cast8(xb  + i * 8, x  + i * 8);
    for (size_t i = g; i < (3145728 / 8); i += stride) cast8(wab + i * 8, wa + i * 8);
    for (size_t i = g; i < (1048576 / 8); i += stride) cast8(wpb + i * 8, wp + i * 8);
}

// ---------------------------------------------------------------------------
// C[M,N] = A[M,K] @ B[N,K]^T, bf16 in, fp32 accum. m97 structure: 128xBN
// tile, BK=32, global_load_lds width=16 into UNPADDED LDS (row = 64B).
// BN=128: waves 2x2, acc[4][4].  BN=64: waves 4x1, acc[2][4] (2x the blocks).
// QKV_SPLIT: col<2048 -> Cqk[row*2048+col] bf16; col>=2048 -> Vt[bh*64+d][t].
// else: Cf[row*N+col] fp32.
// ---------------------------------------------------------------------------
template <bool QKV_SPLIT, int BN>
__global__ __launch_bounds__(256)
void gemm_bt(const unsigned short* __restrict__ A, const unsigned short* __restrict__ B,
             unsigned short* __restrict__ Cqk, float* __restrict__ Cf,
             unsigned short* __restrict__ Vt, int M, int N, int K)
{
    constexpr int WCOLS = (BN == 128) ? 2 : 1;
    constexpr int WROWS = 4 / WCOLS;
    constexpr int MI    = 128 / (16 * WROWS);   // 4 (BN=128) or 2 (BN=64)

    __shared__ __align__(16) unsigned short As[128 * 32];
    __shared__ __align__(16) unsigned short Bs[BN * 32];

    const int tid  = threadIdx.x;
    const int lane = tid & 63;
    const int w    = tid >> 6;
    const int wm   = w / WCOLS, wn = w % WCOLS;
    const int quad = lane >> 4;
    const int lm   = lane & 15;
    const int m0 = blockIdx.y * 128;
    const int n0 = blockIdx.x * BN;
    const int sr = lane >> 2;          // staging row within 16-row group
    const int sc = (lane & 3) * 8;     // staging col (8 shorts = 16B)

    floatx4 acc[MI][4] = {};

    for (int k0 = 0; k0 < K; k0 += 32) {
        __syncthreads();               // WAR: everyone done reading LDS
        #pragma unroll
        for (int i = 0; i < 2; ++i) {  // A: 128 rows
            int r = w * 32 + i * 16;
            glds16(&A[(size_t)(m0 + r + sr) * K + k0 + sc], &As[r * 32]);
        }
        #pragma unroll
        for (int i = 0; i < BN / 64; ++i) {  // B: BN rows
            int r = w * (BN / 4) + i * 16;
            glds16(&B[(size_t)(n0 + r + sr) * K + k0 + sc], &Bs[r * 32]);
        }
        __syncthreads();               // vmcnt(0) drained before barrier

        bf16x8 a[MI];
        #pragma unroll
        for (int i = 0; i < MI; ++i)
            a[i] = *(const bf16x8*)&As[(wm * (16 * MI) + i * 16 + lm) * 32 + quad * 8];
        #pragma unroll
        for (int j = 0; j < 4; ++j) {
            bf16x8 b = *(const bf16x8*)&Bs[(wn * 64 + j * 16 + lm) * 32 + quad * 8];
            #pragma unroll
            for (int i = 0; i < MI; ++i)
                acc[i][j] = __builtin_amdgcn_mfma_f32_16x16x32_bf16(a[i], b, acc[i][j], 0, 0, 0);
        }
    }

    // C/D layout: col = lane&15, row = quad*4 + reg
    #pragma unroll
    for (int i = 0; i < MI; ++i) {
        #pragma unroll
        for (int j = 0; j < 4; ++j) {
            int col = n0 + wn * 64 + j * 16 + lm;
            #pragma unroll
            for (int r = 0; r < 4; ++r) {
                int row = m0 + wm * (16 * MI) + i * 16 + quad * 4 + r;
                if constexpr (QKV_SPLIT) {
                    unsigned short v = f2bf(acc[i][j][r]);
                    if (col < 2048) {
                        Cqk[(size_t)row * 2048 + col] = v;           // q,k thirds
                    } else {
                        int bq = row >> 11, t = row & 2047;          // V -> Vt[bh*64+d][t]
                        Vt[((size_t)(bq * 1024 + (col - 2048))) * 2048 + t] = v;
                    }
                } else {
                    Cf[(size_t)row * N + col] = acc[i][j][r];
                }
            }
        }
    }
}

// ---------------------------------------------------------------------------
// RMSNorm (Dh=64, eps=f32 eps) + rotary, IN PLACE on qk [B,T,2C] bf16.
// ---------------------------------------------------------------------------
__global__ __launch_bounds__(256)
void rmsnorm_rope(unsigned short* __restrict__ qk)
{
    int gw   = (blockIdx.x * 256 + threadIdx.x) >> 6;
    int lane = threadIdx.x & 63;
    int h = gw & 15;
    int t = (gw >> 4) & 2047;
    int b = gw >> 15;

    size_t base = ((size_t)(b * 2048 + t)) * 2048 + h * 64 + lane;
    float q = bf2f(qk[base]);
    float k = bf2f(qk[base + 1024]);

    float sq = q * q, sk = k * k;
    #pragma unroll
    for (int off = 32; off >= 1; off >>= 1) {
        sq += __shfl_xor(sq, off, 64);
        sk += __shfl_xor(sk, off, 64);
    }
    const float eps = 1.1920929e-07f;
    q *= rsqrtf(sq * (1.0f / 64.0f) + eps);
    k *= rsqrtf(sk * (1.0f / 64.0f) + eps);

    int i = lane & 31;
    float ang = (float)t * expf(-(float)i * 0.28782313662425572f);  // ln(1e4)/32
    float c = cosf(ang), s = sinf(ang);
    float qp = __shfl_xor(q, 32, 64);
    float kp = __shfl_xor(k, 32, 64);
    float sgn = (lane < 32) ? -1.0f : 1.0f;
    float qo = q * c + sgn * qp * s;
    float ko = k * c + sgn * kp * s;

    qk[base]        = f2bf(qo);
    qk[base + 1024] = f2bf(ko);
}

// ---------------------------------------------------------------------------
// Flash attention, static-max softmax (RMSNorm => |s|<=8 => p=exp(s-8), no
// rescale, masked entries exactly 0). S^T via mfma(A=K, B=Q): lane holds one
// q-row, key-contiguous P -> packed b64 P writes. Round-5 inner loop verbatim.
// NEW: q-tile pairing — block (bh, p) handles q-tiles {31-p, p}: 512 blocks
// of exactly 33 key-steps each (perfect triangular balance, no drain tail).
// ---------------------------------------------------------------------------
__global__ __launch_bounds__(256)
void attention(const unsigned short* __restrict__ qk,
               const unsigned short* __restrict__ Vt,
               unsigned short* __restrict__ Y)
{
    constexpr int LD = 72;
    __shared__ __align__(16) unsigned short QPs[64 * LD];  // Q stage, then P
    __shared__ __align__(16) unsigned short Ks [64 * LD];
    __shared__ __align__(16) unsigned short Vs [64 * LD];  // rows=d, cols=key

    const int tid  = threadIdx.x;
    const int lane = tid & 63;
    const int w    = tid >> 6;
    const int quad = lane >> 4;
    const int lm   = lane & 15;

    const int bh = blockIdx.x;
    const int b  = bh >> 4, h = bh & 15;

    const unsigned short* kbase = qk + (size_t)b * 2048 * 2048 + 1024 + h * 64;
    const unsigned short* vbase = Vt + (size_t)bh * 64 * 2048;

    #pragma unroll
    for (int sel = 0; sel < 2; ++sel) {
        const int qt = sel ? (int)blockIdx.y : 31 - (int)blockIdx.y;  // big first
        const int q0 = qt * 64;
        const int qrow = q0 + w * 16 + lm;   // this lane's q-row (S^T layout)

        if (sel) __syncthreads();            // QPs reuse across the pair

        // stage Q tile
        #pragma unroll
        for (int i = 0; i < 2; ++i) {
            int c = i * 256 + tid, row = c >> 3, col = (c & 7) * 8;
            *(ushortx8*)&QPs[row * LD + col] =
                *(const ushortx8*)&qk[((size_t)(b * 2048 + q0 + row)) * 2048 + h * 64 + col];
        }

        // prefetch key-tile 0 into regs (static indices only)
        ushortx8 kreg[2], vreg[2];
        #pragma unroll
        for (int i = 0; i < 2; ++i) {
            int c = i * 256 + tid, row = c >> 3, col = (c & 7) * 8;
            kreg[i] = *(const ushortx8*)&kbase[(size_t)row * 2048 + col];
            vreg[i] = *(const ushortx8*)&vbase[(size_t)row * 2048 + col];
        }

        floatx4 o[4] = {};
        float lsum = 0.0f;
        bf16x8 qf[2];
        const float c1 = 0.125f * 1.44269504f;   // scale * log2(e)
        const float c2 = 8.0f   * 1.44269504f;   // static max 8

        for (int kt = 0; kt <= qt; ++kt) {
            const int k0 = kt * 64;
            __syncthreads();
            #pragma unroll
            for (int i = 0; i < 2; ++i) {
                int c = i * 256 + tid, row = c >> 3, col = (c & 7) * 8;
                *(ushortx8*)&Ks[row * LD + col] = kreg[i];
                *(ushortx8*)&Vs[row * LD + col] = vreg[i];
            }
            __syncthreads();

            if (kt == 0) {
                #pragma unroll
                for (int kk = 0; kk < 2; ++kk)
                    qf[kk] = *(const bf16x8*)&QPs[(w * 16 + lm) * LD + kk * 32 + quad * 8];
            }
            if (kt < qt) {
                const int kn = k0 + 64;
                #pragma unroll
                for (int i = 0; i < 2; ++i) {
                    int c = i * 256 + tid, row = c >> 3, col = (c & 7) * 8;
                    kreg[i] = *(const ushortx8*)&kbase[(size_t)(kn + row) * 2048 + col];
                    vreg[i] = *(const ushortx8*)&vbase[(size_t)row * 2048 + kn + col];
                }
            }

            // S^T: lane(quad,lm): q = qrow, key = k0 + j*16 + quad*4 + r
            floatx4 sa[4] = {};
            #pragma unroll
            for (int kk = 0; kk < 2; ++kk) {
                #pragma unroll
                for (int j = 0; j < 4; ++j) {
                    bf16x8 kf = *(const bf16x8*)&Ks[(j * 16 + lm) * LD + kk * 32 + quad * 8];
                    sa[j] = __builtin_amdgcn_mfma_f32_16x16x32_bf16(kf, qf[kk], sa[j], 0, 0, 0);
                }
            }

            // p = exp2(s*c1 - c2); mask; pack 4 key-contiguous bf16 -> b64
            const bool dg = (kt == qt);
            #pragma unroll
            for (int j = 0; j < 4; ++j) {
                int kb = k0 + j * 16 + quad * 4;
                ushortx4 pk;
                #pragma unroll
                for (int r = 0; r < 4; ++r) {
                    float p = exp2f(sa[j][r] * c1 - c2);
                    if (dg && (kb + r) > qrow) p = 0.0f;
                    lsum += p;
                    pk[r] = f2bf(p);
                }
                *(ushortx4*)&QPs[(w * 16 + lm) * LD + j * 16 + quad * 4] = pk;
            }

            // O += P V: A = P (own strip, same-wave LDS RAW), B = V^T
            #pragma unroll
            for (int kk = 0; kk < 2; ++kk) {
                bf16x8 pf = *(const bf16x8*)&QPs[(w * 16 + lm) * LD + kk * 32 + quad * 8];
                #pragma unroll
                for (int j = 0; j < 4; ++j) {
                    bf16x8 vf = *(const bf16x8*)&Vs[(j * 16 + lm) * LD + kk * 32 + quad * 8];
                    o[j] = __builtin_amdgcn_mfma_f32_16x16x32_bf16(pf, vf, o[j], 0, 0, 0);
                }
            }
        }

        // row-sum at lane lm (dup over quads after reduce) -> C-layout rows
        float lt = lsum;
        lt += __shfl_xor(lt, 16, 64);
        lt += __shfl_xor(lt, 32, 64);
        float rv = 1.0f / lt;
        float rinv[4];
        #pragma unroll
        for (int r = 0; r < 4; ++r)
            rinv[r] = __shfl(rv, (quad << 4) + quad * 4 + r, 64);

        #pragma unroll
        for (int j = 0; j < 4; ++j) {
            int colg = h * 64 + j * 16 + lm;
            #pragma unroll
            for (int r = 0; r < 4; ++r) {
                int rowg = q0 + w * 16 + quad * 4 + r;
                Y[((size_t)(b * 2048 + rowg)) * 1024 + colg] = f2bf(o[j][r] * rinv[r]);
            }
        }
    }
}

// ---------------------------------------------------------------------------
extern "C" void kernel_launch(void* const* d_in, const int* in_sizes, int n_in,
                              void* d_out, int out_size, void* d_ws, size_t ws_size,
                              hipStream_t stream)
{
    const float* x      = (const float*)d_in[0];   // [2,2048,1024] fp32
    const float* w_attn = (const float*)d_in[1];   // [3072,1024] fp32
    const float* w_proj = (const float*)d_in[2];   // [1024,1024] fp32
    float* out = (float*)d_out;                    // [2,2048,1024] fp32

    // ws: qk 16.8MB | Vt 8.4MB | y 8.4MB | wpb 2.1MB  (35.7 MB total)
    unsigned short* qkbuf = (unsigned short*)d_ws;
    unsigned short* Vtb   = qkbuf + (size_t)4096 * 2048;
    unsigned short* y     = Vtb   + (size_t)32 * 64 * 2048;
    unsigned short* wpb   = y     + (size_t)4096 * 1024;
    // d_out doubles as pre-cast scratch for xb/wab (dead before proj writes):
    unsigned short* xb  = (unsigned short*)d_out;             // 8.4MB
    unsigned short* wab = xb + (size_t)4096 * 1024;           // 6.3MB

    dim3 blk(256);
    cast_inputs<<<dim3(1024), blk, 0, stream>>>(x, w_attn, w_proj, xb, wab, wpb);
    gemm_bt<true, 128>
        <<<dim3(24, 32), blk, 0, stream>>>(xb, wab, qkbuf, nullptr, Vtb, 4096, 3072, 1024);
    rmsnorm_rope<<<dim3(16384), blk, 0, stream>>>(qkbuf);
    attention<<<dim3(32, 16), blk, 0, stream>>>(qkbuf, Vtb, y);
    gemm_bt<false, 64>
        <<<dim3(16, 32), blk, 0, stream>>>(y, wpb, nullptr, out, nullptr, 4096, 1024, 1024);
}

// Round 8
// 195.965 us; speedup vs baseline: 3.6727x; 1.0690x over previous
//
#include <hip/hip_runtime.h>
#include <cstdint>
#include <cstddef>

// CausalSelfAttention MI355X (gfx950). fp32 I/O, bf16 MFMA compute, fp32 accum.
// B=2, T=2048, C=1024, H=16, Dh=64.
// [cast f32->bf16] -> [gemm qkv (global_load_lds), V stored transposed w/ b64
// packed stores] -> [rmsnorm+rope in-place] -> [flash attention: S^T layout,
// static-max softmax, peeled diagonal step, MFMA row-sums] -> [gemm proj BN=64]
// Round-6 lesson: NEVER dynamically index register arrays (select-tree/scratch
// explosion, 10x). Everything here is statically indexed.

typedef short bf16x8 __attribute__((ext_vector_type(8)));
typedef float floatx4 __attribute__((ext_vector_type(4)));
typedef unsigned short ushortx8 __attribute__((ext_vector_type(8)));
typedef unsigned short ushortx4 __attribute__((ext_vector_type(4)));
typedef unsigned int uintx2 __attribute__((ext_vector_type(2)));

#define DEVI __device__ __forceinline__

DEVI float bf2f(unsigned short u) {
    unsigned int x = ((unsigned int)u) << 16;
    return __builtin_bit_cast(float, x);
}
DEVI unsigned short f2bf(float f) {
    unsigned int u = __builtin_bit_cast(unsigned int, f);
    u += 0x7fffu + ((u >> 16) & 1u);   // RNE; finite values only
    return (unsigned short)(u >> 16);
}
// pack 2 fp32 -> 2 bf16 in one dword (round-half-up; inputs >= 0 here):
// result = [a.hi16 | b.hi16<<16]  (a = element 0 in memory, little-endian)
DEVI unsigned int pkbf2(float a, float b) {
    unsigned int ua = __builtin_bit_cast(unsigned int, a) + 0x8000u;
    unsigned int ub = __builtin_bit_cast(unsigned int, b) + 0x8000u;
    return __builtin_amdgcn_perm(ub, ua, 0x07060302);
}

// async global->LDS, 16B per lane; LDS dest = wave-uniform base + lane*16.
DEVI void glds16(const unsigned short* g, unsigned short* l) {
    __builtin_amdgcn_global_load_lds(
        (const __attribute__((address_space(1))) unsigned int*)g,
        (__attribute__((address_space(3))) unsigned int*)l, 16, 0, 0);
}

DEVI void cast8(unsigned short* dst, const float* src) {
    floatx4 a = *(const floatx4*)src;
    floatx4 b = *(const floatx4*)(src + 4);
    ushortx8 o;
    o[0] = f2bf(a[0]); o[1] = f2bf(a[1]); o[2] = f2bf(a[2]); o[3] = f2bf(a[3]);
    o[4] = f2bf(b[0]); o[5] = f2bf(b[1]); o[6] = f2bf(b[2]); o[7] = f2bf(b[3]);
    *(ushortx8*)dst = o;
}

// ---------------------------------------------------------------------------
__global__ __launch_bounds__(256)
void cast_inputs(const float* __restrict__ x, const float* __restrict__ wa,
                 const float* __restrict__ wp,
                 unsigned short* __restrict__ xb, unsigned short* __restrict__ wab,
                 unsigned short* __restrict__ wpb)
{
    size_t g = (size_t)blockIdx.x * 256 + threadIdx.x;
    size_t stride = (size_t)gridDim.x * 256;
    for (size_t i = g; i < (4194304 / 8); i += stride) cast8(xb  + i * 8, x  + i * 8);
    for (size_t i = g; i < (3145728 / 8); i += stride) cast8(wab + i * 8, wa + i * 8);
    for (size_t i = g; i < (1048576 / 8); i += stride) cast8(wpb + i * 8, wp + i * 8);
}

// ---------------------------------------------------------------------------
// C[M,N] = A[M,K] @ B[N,K]^T, bf16 in, fp32 accum. m97 structure: 128xBN
// tile, BK=32, global_load_lds width=16 into UNPADDED LDS (row = 64B).
// BN=128: waves 2x2, acc[4][4].  BN=64: waves 4x1, acc[2][4] (2x the blocks).
// QKV_SPLIT: col<2048 -> Cqk[row*2048+col] bf16; col>=2048 -> Vt[bh*64+d][t]
// with 4 consecutive-t values packed into one b64 store.
// ---------------------------------------------------------------------------
template <bool QKV_SPLIT, int BN>
__global__ __launch_bounds__(256)
void gemm_bt(const unsigned short* __restrict__ A, const unsigned short* __restrict__ B,
             unsigned short* __restrict__ Cqk, float* __restrict__ Cf,
             unsigned short* __restrict__ Vt, int M, int N, int K)
{
    constexpr int WCOLS = (BN == 128) ? 2 : 1;
    constexpr int WROWS = 4 / WCOLS;
    constexpr int MI    = 128 / (16 * WROWS);   // 4 (BN=128) or 2 (BN=64)

    __shared__ __align__(16) unsigned short As[128 * 32];
    __shared__ __align__(16) unsigned short Bs[BN * 32];

    const int tid  = threadIdx.x;
    const int lane = tid & 63;
    const int w    = tid >> 6;
    const int wm   = w / WCOLS, wn = w % WCOLS;
    const int quad = lane >> 4;
    const int lm   = lane & 15;
    const int m0 = blockIdx.y * 128;
    const int n0 = blockIdx.x * BN;
    const int sr = lane >> 2;          // staging row within 16-row group
    const int sc = (lane & 3) * 8;     // staging col (8 shorts = 16B)

    floatx4 acc[MI][4] = {};

    for (int k0 = 0; k0 < K; k0 += 32) {
        __syncthreads();               // WAR: everyone done reading LDS
        #pragma unroll
        for (int i = 0; i < 2; ++i) {  // A: 128 rows
            int r = w * 32 + i * 16;
            glds16(&A[(size_t)(m0 + r + sr) * K + k0 + sc], &As[r * 32]);
        }
        #pragma unroll
        for (int i = 0; i < BN / 64; ++i) {  // B: BN rows
            int r = w * (BN / 4) + i * 16;
            glds16(&B[(size_t)(n0 + r + sr) * K + k0 + sc], &Bs[r * 32]);
        }
        __syncthreads();               // vmcnt(0) drained before barrier

        bf16x8 a[MI];
        #pragma unroll
        for (int i = 0; i < MI; ++i)
            a[i] = *(const bf16x8*)&As[(wm * (16 * MI) + i * 16 + lm) * 32 + quad * 8];
        #pragma unroll
        for (int j = 0; j < 4; ++j) {
            bf16x8 b = *(const bf16x8*)&Bs[(wn * 64 + j * 16 + lm) * 32 + quad * 8];
            #pragma unroll
            for (int i = 0; i < MI; ++i)
                acc[i][j] = __builtin_amdgcn_mfma_f32_16x16x32_bf16(a[i], b, acc[i][j], 0, 0, 0);
        }
    }

    // C/D layout: col = lane&15, row = quad*4 + reg
    #pragma unroll
    for (int i = 0; i < MI; ++i) {
        #pragma unroll
        for (int j = 0; j < 4; ++j) {
            int col = n0 + wn * 64 + j * 16 + lm;
            int row0 = m0 + wm * (16 * MI) + i * 16 + quad * 4;   // rows row0..row0+3
            if constexpr (QKV_SPLIT) {
                if (col < 2048) {
                    #pragma unroll
                    for (int r = 0; r < 4; ++r)
                        Cqk[(size_t)(row0 + r) * 2048 + col] = f2bf(acc[i][j][r]);
                } else {
                    // V -> Vt[(b*16+h)*64+d][t]; rows are consecutive t -> b64 pack
                    int bq = row0 >> 11, t0 = row0 & 2047;
                    ushortx4 pk;
                    #pragma unroll
                    for (int r = 0; r < 4; ++r) pk[r] = f2bf(acc[i][j][r]);
                    *(ushortx4*)&Vt[((size_t)(bq * 1024 + (col - 2048))) * 2048 + t0] = pk;
                }
            } else {
                #pragma unroll
                for (int r = 0; r < 4; ++r)
                    Cf[(size_t)(row0 + r) * N + col] = acc[i][j][r];
            }
        }
    }
}

// ---------------------------------------------------------------------------
// RMSNorm (Dh=64, eps=f32 eps) + rotary, IN PLACE on qk [B,T,2C] bf16.
// ---------------------------------------------------------------------------
__global__ __launch_bounds__(256)
void rmsnorm_rope(unsigned short* __restrict__ qk)
{
    int gw   = (blockIdx.x * 256 + threadIdx.x) >> 6;
    int lane = threadIdx.x & 63;
    int h = gw & 15;
    int t = (gw >> 4) & 2047;
    int b = gw >> 15;

    size_t base = ((size_t)(b * 2048 + t)) * 2048 + h * 64 + lane;
    float q = bf2f(qk[base]);
    float k = bf2f(qk[base + 1024]);

    float sq = q * q, sk = k * k;
    #pragma unroll
    for (int off = 32; off >= 1; off >>= 1) {
        sq += __shfl_xor(sq, off, 64);
        sk += __shfl_xor(sk, off, 64);
    }
    const float eps = 1.1920929e-07f;
    q *= rsqrtf(sq * (1.0f / 64.0f) + eps);
    k *= rsqrtf(sk * (1.0f / 64.0f) + eps);

    int i = lane & 31;
    float ang = (float)t * expf(-(float)i * 0.28782313662425572f);  // ln(1e4)/32
    float c = cosf(ang), s = sinf(ang);
    float qp = __shfl_xor(q, 32, 64);
    float kp = __shfl_xor(k, 32, 64);
    float sgn = (lane < 32) ? -1.0f : 1.0f;
    float qo = q * c + sgn * qp * s;
    float ko = k * c + sgn * kp * s;

    qk[base]        = f2bf(qo);
    qk[base + 1024] = f2bf(ko);
}

// ---------------------------------------------------------------------------
// Flash attention, static-max softmax (RMSNorm => |s|<=8 => p=exp(s-8), no
// rescale; masked entries exactly 0). S^T via mfma(A=K, B=Q): lane holds one
// q-row, key-contiguous P -> packed b64 P writes.
// This round: peeled diagonal step (main loop mask-free), row-sums via
// mfma(P, ones) into l_acc (same D-layout as o => no end shuffles), perm-pack
// P, pointer-increment prefetch addressing. Grid back to 1024 blocks.
// ---------------------------------------------------------------------------
__global__ __launch_bounds__(256)
void attention(const unsigned short* __restrict__ qk,
               const unsigned short* __restrict__ Vt,
               unsigned short* __restrict__ Y)
{
    constexpr int LD = 72;
    __shared__ __align__(16) unsigned short QPs[64 * LD];  // Q stage, then P
    __shared__ __align__(16) unsigned short Ks [64 * LD];
    __shared__ __align__(16) unsigned short Vs [64 * LD];  // rows=d, cols=key

    const int tid  = threadIdx.x;
    const int lane = tid & 63;
    const int w    = tid >> 6;
    const int quad = lane >> 4;
    const int lm   = lane & 15;

    const int bh = blockIdx.x;
    const int qt = 31 - blockIdx.y;      // longest first
    const int b  = bh >> 4, h = bh & 15;
    const int q0 = qt * 64;
    const int qrow = q0 + w * 16 + lm;   // this lane's q-row (S^T layout)

    // per-thread staging coords: chunk i covers rows i*32.., 8 cols of 8
    const int r0 = tid >> 3, r1 = r0 + 32, pc = (tid & 7) * 8;
    const unsigned short* kp0 = qk + (size_t)b * 2048 * 2048 + 1024 + h * 64
                              + (size_t)r0 * 2048 + pc;
    const unsigned short* kp1 = kp0 + (size_t)32 * 2048;
    const unsigned short* vp0 = Vt + (size_t)bh * 64 * 2048 + (size_t)r0 * 2048 + pc;
    const unsigned short* vp1 = vp0 + (size_t)32 * 2048;

    // stage Q tile
    #pragma unroll
    for (int i = 0; i < 2; ++i) {
        int c = i * 256 + tid, row = c >> 3, col = (c & 7) * 8;
        *(ushortx8*)&QPs[row * LD + col] =
            *(const ushortx8*)&qk[((size_t)(b * 2048 + q0 + row)) * 2048 + h * 64 + col];
    }

    // prefetch key-tile 0
    ushortx8 kreg0 = *(const ushortx8*)kp0, kreg1 = *(const ushortx8*)kp1;
    ushortx8 vreg0 = *(const ushortx8*)vp0, vreg1 = *(const ushortx8*)vp1;
    kp0 += (size_t)64 * 2048; kp1 += (size_t)64 * 2048;
    vp0 += 64; vp1 += 64;

    __syncthreads();                     // Q staging visible
    bf16x8 qf[2];
    #pragma unroll
    for (int kk = 0; kk < 2; ++kk)
        qf[kk] = *(const bf16x8*)&QPs[(w * 16 + lm) * LD + kk * 32 + quad * 8];

    bf16x8 ones;
    #pragma unroll
    for (int i = 0; i < 8; ++i) ones[i] = (short)0x3F80;   // bf16 1.0

    floatx4 o[4] = {};
    floatx4 l_acc = {};                  // row-sums, same D-layout rows as o
    const float c1 = 0.125f * 1.44269504f;   // scale * log2(e)
    const float c2 = 8.0f   * 1.44269504f;   // static max 8

    // ---- main loop: kt in [0, qt) — NO masking (all keys < q0 <= qrow) ----
    for (int kt = 0; kt < qt; ++kt) {
        __syncthreads();                 // prev tile consumed
        *(ushortx8*)&Ks[r0 * LD + pc] = kreg0;
        *(ushortx8*)&Ks[r1 * LD + pc] = kreg1;
        *(ushortx8*)&Vs[r0 * LD + pc] = vreg0;
        *(ushortx8*)&Vs[r1 * LD + pc] = vreg1;
        __syncthreads();                 // staging visible

        // prefetch next tile (kt+1 <= qt always valid here)
        kreg0 = *(const ushortx8*)kp0; kreg1 = *(const ushortx8*)kp1;
        vreg0 = *(const ushortx8*)vp0; vreg1 = *(const ushortx8*)vp1;
        kp0 += (size_t)64 * 2048; kp1 += (size_t)64 * 2048;
        vp0 += 64; vp1 += 64;

        floatx4 sa[4] = {};
        #pragma unroll
        for (int kk = 0; kk < 2; ++kk)
            #pragma unroll
            for (int j = 0; j < 4; ++j) {
                bf16x8 kf = *(const bf16x8*)&Ks[(j * 16 + lm) * LD + kk * 32 + quad * 8];
                sa[j] = __builtin_amdgcn_mfma_f32_16x16x32_bf16(kf, qf[kk], sa[j], 0, 0, 0);
            }

        #pragma unroll
        for (int j = 0; j < 4; ++j) {
            float p0 = exp2f(sa[j][0] * c1 - c2);
            float p1 = exp2f(sa[j][1] * c1 - c2);
            float p2 = exp2f(sa[j][2] * c1 - c2);
            float p3 = exp2f(sa[j][3] * c1 - c2);
            uintx2 pk;
            pk[0] = pkbf2(p0, p1);
            pk[1] = pkbf2(p2, p3);
            *(uintx2*)&QPs[(w * 16 + lm) * LD + j * 16 + quad * 4] = pk;
        }

        #pragma unroll
        for (int kk = 0; kk < 2; ++kk) {
            bf16x8 pf = *(const bf16x8*)&QPs[(w * 16 + lm) * LD + kk * 32 + quad * 8];
            #pragma unroll
            for (int j = 0; j < 4; ++j) {
                bf16x8 vf = *(const bf16x8*)&Vs[(j * 16 + lm) * LD + kk * 32 + quad * 8];
                o[j] = __builtin_amdgcn_mfma_f32_16x16x32_bf16(pf, vf, o[j], 0, 0, 0);
            }
            l_acc = __builtin_amdgcn_mfma_f32_16x16x32_bf16(pf, ones, l_acc, 0, 0, 0);
        }
    }

    // ---- peeled diagonal step: kt == qt, causal mask applied ----
    {
        __syncthreads();
        *(ushortx8*)&Ks[r0 * LD + pc] = kreg0;
        *(ushortx8*)&Ks[r1 * LD + pc] = kreg1;
        *(ushortx8*)&Vs[r0 * LD + pc] = vreg0;
        *(ushortx8*)&Vs[r1 * LD + pc] = vreg1;
        __syncthreads();

        floatx4 sa[4] = {};
        #pragma unroll
        for (int kk = 0; kk < 2; ++kk)
            #pragma unroll
            for (int j = 0; j < 4; ++j) {
                bf16x8 kf = *(const bf16x8*)&Ks[(j * 16 + lm) * LD + kk * 32 + quad * 8];
                sa[j] = __builtin_amdgcn_mfma_f32_16x16x32_bf16(kf, qf[kk], sa[j], 0, 0, 0);
            }

        #pragma unroll
        for (int j = 0; j < 4; ++j) {
            int kb = q0 + j * 16 + quad * 4;
            float p0 = (kb + 0 > qrow) ? 0.0f : exp2f(sa[j][0] * c1 - c2);
            float p1 = (kb + 1 > qrow) ? 0.0f : exp2f(sa[j][1] * c1 - c2);
            float p2 = (kb + 2 > qrow) ? 0.0f : exp2f(sa[j][2] * c1 - c2);
            float p3 = (kb + 3 > qrow) ? 0.0f : exp2f(sa[j][3] * c1 - c2);
            uintx2 pk;
            pk[0] = pkbf2(p0, p1);
            pk[1] = pkbf2(p2, p3);
            *(uintx2*)&QPs[(w * 16 + lm) * LD + j * 16 + quad * 4] = pk;
        }

        #pragma unroll
        for (int kk = 0; kk < 2; ++kk) {
            bf16x8 pf = *(const bf16x8*)&QPs[(w * 16 + lm) * LD + kk * 32 + quad * 8];
            #pragma unroll
            for (int j = 0; j < 4; ++j) {
                bf16x8 vf = *(const bf16x8*)&Vs[(j * 16 + lm) * LD + kk * 32 + quad * 8];
                o[j] = __builtin_amdgcn_mfma_f32_16x16x32_bf16(pf, vf, o[j], 0, 0, 0);
            }
            l_acc = __builtin_amdgcn_mfma_f32_16x16x32_bf16(pf, ones, l_acc, 0, 0, 0);
        }
    }

    // epilogue: l_acc rows == o rows (D-layout); no shuffles needed
    float rinv[4];
    #pragma unroll
    for (int r = 0; r < 4; ++r) rinv[r] = 1.0f / l_acc[r];

    #pragma unroll
    for (int j = 0; j < 4; ++j) {
        int colg = h * 64 + j * 16 + lm;
        #pragma unroll
        for (int r = 0; r < 4; ++r) {
            int rowg = q0 + w * 16 + quad * 4 + r;
            Y[((size_t)(b * 2048 + rowg)) * 1024 + colg] = f2bf(o[j][r] * rinv[r]);
        }
    }
}

// ---------------------------------------------------------------------------
extern "C" void kernel_launch(void* const* d_in, const int* in_sizes, int n_in,
                              void* d_out, int out_size, void* d_ws, size_t ws_size,
                              hipStream_t stream)
{
    const float* x      = (const float*)d_in[0];   // [2,2048,1024] fp32
    const float* w_attn = (const float*)d_in[1];   // [3072,1024] fp32
    const float* w_proj = (const float*)d_in[2];   // [1024,1024] fp32
    float* out = (float*)d_out;                    // [2,2048,1024] fp32

    // ws: qk 16.8MB | Vt 8.4MB | y 8.4MB | wpb 2.1MB  (35.7 MB total)
    unsigned short* qkbuf = (unsigned short*)d_ws;
    unsigned short* Vtb   = qkbuf + (size_t)4096 * 2048;
    unsigned short* y     = Vtb   + (size_t)32 * 64 * 2048;
    unsigned short* wpb   = y     + (size_t)4096 * 1024;
    // d_out doubles as pre-cast scratch for xb/wab (dead before proj writes):
    unsigned short* xb  = (unsigned short*)d_out;             // 8.4MB
    unsigned short* wab = xb + (size_t)4096 * 1024;           // 6.3MB

    dim3 blk(256);
    cast_inputs<<<dim3(1024), blk, 0, stream>>>(x, w_attn, w_proj, xb, wab, wpb);
    gemm_bt<true, 128>
        <<<dim3(24, 32), blk, 0, stream>>>(xb, wab, qkbuf, nullptr, Vtb, 4096, 3072, 1024);
    rmsnorm_rope<<<dim3(16384), blk, 0, stream>>>(qkbuf);
    attention<<<dim3(32, 32), blk, 0, stream>>>(qkbuf, Vtb, y);
    gemm_bt<false, 64>
        <<<dim3(16, 32), blk, 0, stream>>>(y, wpb, nullptr, out, nullptr, 4096, 1024, 1024);
}

// Round 9
// 184.068 us; speedup vs baseline: 3.9101x; 1.0646x over previous
//
#include <hip/hip_runtime.h>
#include <cstdint>
#include <cstddef>

// CausalSelfAttention MI355X (gfx950). fp32 I/O, bf16 MFMA compute, fp32 accum.
// B=2, T=2048, C=1024, H=16, Dh=64.
// [cast f32->bf16] -> [gemm qkv (global_load_lds) with FUSED rmsnorm+rope
// epilogue on q/k and transposed-packed V stores] -> [flash attention: S^T,
// static-max softmax, peeled diagonal, MFMA row-sums] -> [gemm proj BN=64 BK=64]
// Round-6 lesson: NEVER dynamically index register arrays. All static here.

typedef short bf16x8 __attribute__((ext_vector_type(8)));
typedef float floatx4 __attribute__((ext_vector_type(4)));
typedef unsigned short ushortx8 __attribute__((ext_vector_type(8)));
typedef unsigned short ushortx4 __attribute__((ext_vector_type(4)));
typedef unsigned int uintx2 __attribute__((ext_vector_type(2)));

#define DEVI __device__ __forceinline__

DEVI float bf2f(unsigned short u) {
    unsigned int x = ((unsigned int)u) << 16;
    return __builtin_bit_cast(float, x);
}
DEVI unsigned short f2bf(float f) {
    unsigned int u = __builtin_bit_cast(unsigned int, f);
    u += 0x7fffu + ((u >> 16) & 1u);   // RNE; finite values only
    return (unsigned short)(u >> 16);
}
// pack 2 fp32 -> 2 bf16 in one dword (round-half-up; inputs >= 0 here)
DEVI unsigned int pkbf2(float a, float b) {
    unsigned int ua = __builtin_bit_cast(unsigned int, a) + 0x8000u;
    unsigned int ub = __builtin_bit_cast(unsigned int, b) + 0x8000u;
    return __builtin_amdgcn_perm(ub, ua, 0x07060302);
}

// async global->LDS, 16B per lane; LDS dest = wave-uniform base + lane*16.
DEVI void glds16(const unsigned short* g, unsigned short* l) {
    __builtin_amdgcn_global_load_lds(
        (const __attribute__((address_space(1))) unsigned int*)g,
        (__attribute__((address_space(3))) unsigned int*)l, 16, 0, 0);
}

DEVI void cast8(unsigned short* dst, const float* src) {
    floatx4 a = *(const floatx4*)src;
    floatx4 b = *(const floatx4*)(src + 4);
    ushortx8 o;
    o[0] = f2bf(a[0]); o[1] = f2bf(a[1]); o[2] = f2bf(a[2]); o[3] = f2bf(a[3]);
    o[4] = f2bf(b[0]); o[5] = f2bf(b[1]); o[6] = f2bf(b[2]); o[7] = f2bf(b[3]);
    *(ushortx8*)dst = o;
}

// ---------------------------------------------------------------------------
__global__ __launch_bounds__(256)
void cast_inputs(const float* __restrict__ x, const float* __restrict__ wa,
                 const float* __restrict__ wp,
                 unsigned short* __restrict__ xb, unsigned short* __restrict__ wab,
                 unsigned short* __restrict__ wpb)
{
    size_t g = (size_t)blockIdx.x * 256 + threadIdx.x;
    size_t stride = (size_t)gridDim.x * 256;
    for (size_t i = g; i < (4194304 / 8); i += stride) cast8(xb  + i * 8, x  + i * 8);
    for (size_t i = g; i < (3145728 / 8); i += stride) cast8(wab + i * 8, wa + i * 8);
    for (size_t i = g; i < (1048576 / 8); i += stride) cast8(wpb + i * 8, wp + i * 8);
}

// ---------------------------------------------------------------------------
// C[M,N] = A[M,K] @ B[N,K]^T, bf16 in, fp32 accum. m97 structure: 128xBN
// tile, BK in {32,64}, global_load_lds width=16 into UNPADDED LDS.
// QKV_SPLIT epilogue:
//   col < 2048 (q,k): FUSED RMSNorm(eps=f32eps over Dh=64) + RoPE, then bf16
//     store to Cqk[row*2048+col]. Wave wn owns exactly one head's 64 cols;
//     rotate_half partner d^32 = acc[i][j^2][r] (same lane).
//   col >= 2048 (v): transposed to Vt[(b*16+h)*64+d][t], 4 consecutive-t
//     values packed per b64 store.
// else: Cf[row*N+col] = fp32.
// ---------------------------------------------------------------------------
template <bool QKV_SPLIT, int BN, int BK>
__global__ __launch_bounds__(256)
void gemm_bt(const unsigned short* __restrict__ A, const unsigned short* __restrict__ B,
             unsigned short* __restrict__ Cqk, float* __restrict__ Cf,
             unsigned short* __restrict__ Vt, int M, int N, int K)
{
    constexpr int WCOLS = (BN == 128) ? 2 : 1;
    constexpr int WROWS = 4 / WCOLS;
    constexpr int MI    = 128 / (16 * WROWS);   // 4 (BN=128) or 2 (BN=64)
    constexpr int LPR   = BK / 8;               // lanes per LDS row (16B each)
    constexpr int RPI   = 64 / LPR;             // rows covered per glds16

    __shared__ __align__(16) unsigned short As[128 * BK];
    __shared__ __align__(16) unsigned short Bs[BN * BK];

    const int tid  = threadIdx.x;
    const int lane = tid & 63;
    const int w    = tid >> 6;
    const int wm   = w / WCOLS, wn = w % WCOLS;
    const int quad = lane >> 4;
    const int lm   = lane & 15;
    const int m0 = blockIdx.y * 128;
    const int n0 = blockIdx.x * BN;
    const int sr = lane / LPR;          // staging row within RPI-row group
    const int sc = (lane % LPR) * 8;    // staging col (8 shorts = 16B)

    floatx4 acc[MI][4] = {};

    for (int k0 = 0; k0 < K; k0 += BK) {
        __syncthreads();               // WAR: everyone done reading LDS
        #pragma unroll
        for (int i = 0; i < 32 / RPI; ++i) {    // A: 128 rows, 32/wave
            int r = w * 32 + i * RPI;
            glds16(&A[(size_t)(m0 + r + sr) * K + k0 + sc], &As[r * BK]);
        }
        #pragma unroll
        for (int i = 0; i < (BN / 4) / RPI; ++i) {  // B: BN rows, BN/4 per wave
            int r = w * (BN / 4) + i * RPI;
            glds16(&B[(size_t)(n0 + r + sr) * K + k0 + sc], &Bs[r * BK]);
        }
        __syncthreads();               // vmcnt(0) drained before barrier

        #pragma unroll
        for (int kk = 0; kk < BK / 32; ++kk) {
            bf16x8 a[MI];
            #pragma unroll
            for (int i = 0; i < MI; ++i)
                a[i] = *(const bf16x8*)&As[(wm * (16 * MI) + i * 16 + lm) * BK + kk * 32 + quad * 8];
            #pragma unroll
            for (int j = 0; j < 4; ++j) {
                bf16x8 b = *(const bf16x8*)&Bs[(wn * 64 + j * 16 + lm) * BK + kk * 32 + quad * 8];
                #pragma unroll
                for (int i = 0; i < MI; ++i)
                    acc[i][j] = __builtin_amdgcn_mfma_f32_16x16x32_bf16(a[i], b, acc[i][j], 0, 0, 0);
            }
        }
    }

    // C/D layout: col = lane&15 (+16j), row = quad*4 + reg
    if constexpr (QKV_SPLIT) {
        const bool is_v = (n0 + wn * 64) >= 2048;   // wave-uniform
        if (!is_v) {
            // ---- fused RMSNorm + RoPE on q/k ----
            float rn[MI][4];
            #pragma unroll
            for (int i = 0; i < MI; ++i)
                #pragma unroll
                for (int r = 0; r < 4; ++r) {
                    float s = 0.0f;
                    #pragma unroll
                    for (int j = 0; j < 4; ++j) s += acc[i][j][r] * acc[i][j][r];
                    s += __shfl_xor(s, 1, 64);
                    s += __shfl_xor(s, 2, 64);
                    s += __shfl_xor(s, 4, 64);
                    s += __shfl_xor(s, 8, 64);   // sum over the 16 lm lanes
                    rn[i][r] = rsqrtf(s * (1.0f / 64.0f) + 1.1920929e-07f);
                }
            float invf[4];
            #pragma unroll
            for (int j = 0; j < 4; ++j) {
                int d = j * 16 + lm;
                invf[j] = __expf(-(float)(d & 31) * 0.28782313662425572f); // ln(1e4)/32
            }
            #pragma unroll
            for (int i = 0; i < MI; ++i)
                #pragma unroll
                for (int r = 0; r < 4; ++r) {
                    int row = m0 + wm * (16 * MI) + i * 16 + quad * 4 + r;
                    float t = (float)(row & 2047);
                    float g = rn[i][r];
                    #pragma unroll
                    for (int j = 0; j < 4; ++j) {
                        int d = j * 16 + lm;
                        float sn, cs;
                        __sincosf(t * invf[j], &sn, &cs);
                        float v  = acc[i][j][r] * g;
                        float vp = acc[i][j ^ 2][r] * g;          // partner d^32
                        float sgn = (d < 32) ? -1.0f : 1.0f;      // (-x2, x1)
                        Cqk[(size_t)row * 2048 + (n0 + wn * 64 + d)] =
                            f2bf(v * cs + sgn * vp * sn);
                    }
                }
        } else {
            // ---- V: transposed, b64-packed ----
            #pragma unroll
            for (int i = 0; i < MI; ++i)
                #pragma unroll
                for (int j = 0; j < 4; ++j) {
                    int col  = n0 + wn * 64 + j * 16 + lm;
                    int row0 = m0 + wm * (16 * MI) + i * 16 + quad * 4;
                    int bq = row0 >> 11, t0 = row0 & 2047;
                    ushortx4 pk;
                    #pragma unroll
                    for (int r = 0; r < 4; ++r) pk[r] = f2bf(acc[i][j][r]);
                    *(ushortx4*)&Vt[((size_t)(bq * 1024 + (col - 2048))) * 2048 + t0] = pk;
                }
        }
    } else {
        #pragma unroll
        for (int i = 0; i < MI; ++i)
            #pragma unroll
            for (int j = 0; j < 4; ++j) {
                int col  = n0 + wn * 64 + j * 16 + lm;
                int row0 = m0 + wm * (16 * MI) + i * 16 + quad * 4;
                #pragma unroll
                for (int r = 0; r < 4; ++r)
                    Cf[(size_t)(row0 + r) * N + col] = acc[i][j][r];
            }
    }
}

// ---------------------------------------------------------------------------
// Flash attention, static-max softmax (RMSNorm => |s|<=8 => p=exp(s-8), no
// rescale; masked entries exactly 0). S^T via mfma(A=K, B=Q): lane holds one
// q-row, key-contiguous P -> packed b64 P writes. Peeled diagonal step,
// row-sums via mfma(P, ones) (same D-layout as o), pointer-increment prefetch.
// ---------------------------------------------------------------------------
__global__ __launch_bounds__(256)
void attention(const unsigned short* __restrict__ qk,
               const unsigned short* __restrict__ Vt,
               unsigned short* __restrict__ Y)
{
    constexpr int LD = 72;
    __shared__ __align__(16) unsigned short QPs[64 * LD];  // Q stage, then P
    __shared__ __align__(16) unsigned short Ks [64 * LD];
    __shared__ __align__(16) unsigned short Vs [64 * LD];  // rows=d, cols=key

    const int tid  = threadIdx.x;
    const int lane = tid & 63;
    const int w    = tid >> 6;
    const int quad = lane >> 4;
    const int lm   = lane & 15;

    const int bh = blockIdx.x;
    const int qt = 31 - blockIdx.y;      // longest first
    const int b  = bh >> 4, h = bh & 15;
    const int q0 = qt * 64;
    const int qrow = q0 + w * 16 + lm;   // this lane's q-row (S^T layout)

    const int r0 = tid >> 3, r1 = r0 + 32, pc = (tid & 7) * 8;
    const unsigned short* kp0 = qk + (size_t)b * 2048 * 2048 + 1024 + h * 64
                              + (size_t)r0 * 2048 + pc;
    const unsigned short* kp1 = kp0 + (size_t)32 * 2048;
    const unsigned short* vp0 = Vt + (size_t)bh * 64 * 2048 + (size_t)r0 * 2048 + pc;
    const unsigned short* vp1 = vp0 + (size_t)32 * 2048;

    // stage Q tile
    #pragma unroll
    for (int i = 0; i < 2; ++i) {
        int c = i * 256 + tid, row = c >> 3, col = (c & 7) * 8;
        *(ushortx8*)&QPs[row * LD + col] =
            *(const ushortx8*)&qk[((size_t)(b * 2048 + q0 + row)) * 2048 + h * 64 + col];
    }

    // prefetch key-tile 0
    ushortx8 kreg0 = *(const ushortx8*)kp0, kreg1 = *(const ushortx8*)kp1;
    ushortx8 vreg0 = *(const ushortx8*)vp0, vreg1 = *(const ushortx8*)vp1;
    kp0 += (size_t)64 * 2048; kp1 += (size_t)64 * 2048;
    vp0 += 64; vp1 += 64;

    __syncthreads();                     // Q staging visible
    bf16x8 qf[2];
    #pragma unroll
    for (int kk = 0; kk < 2; ++kk)
        qf[kk] = *(const bf16x8*)&QPs[(w * 16 + lm) * LD + kk * 32 + quad * 8];

    bf16x8 ones;
    #pragma unroll
    for (int i = 0; i < 8; ++i) ones[i] = (short)0x3F80;   // bf16 1.0

    floatx4 o[4] = {};
    floatx4 l_acc = {};                  // row-sums, same D-layout rows as o
    const float c1 = 0.125f * 1.44269504f;   // scale * log2(e)
    const float c2 = 8.0f   * 1.44269504f;   // static max 8

    for (int kt = 0; kt < qt; ++kt) {    // mask-free main loop
        __syncthreads();
        *(ushortx8*)&Ks[r0 * LD + pc] = kreg0;
        *(ushortx8*)&Ks[r1 * LD + pc] = kreg1;
        *(ushortx8*)&Vs[r0 * LD + pc] = vreg0;
        *(ushortx8*)&Vs[r1 * LD + pc] = vreg1;
        __syncthreads();

        kreg0 = *(const ushortx8*)kp0; kreg1 = *(const ushortx8*)kp1;
        vreg0 = *(const ushortx8*)vp0; vreg1 = *(const ushortx8*)vp1;
        kp0 += (size_t)64 * 2048; kp1 += (size_t)64 * 2048;
        vp0 += 64; vp1 += 64;

        floatx4 sa[4] = {};
        #pragma unroll
        for (int kk = 0; kk < 2; ++kk)
            #pragma unroll
            for (int j = 0; j < 4; ++j) {
                bf16x8 kf = *(const bf16x8*)&Ks[(j * 16 + lm) * LD + kk * 32 + quad * 8];
                sa[j] = __builtin_amdgcn_mfma_f32_16x16x32_bf16(kf, qf[kk], sa[j], 0, 0, 0);
            }

        #pragma unroll
        for (int j = 0; j < 4; ++j) {
            float p0 = exp2f(sa[j][0] * c1 - c2);
            float p1 = exp2f(sa[j][1] * c1 - c2);
            float p2 = exp2f(sa[j][2] * c1 - c2);
            float p3 = exp2f(sa[j][3] * c1 - c2);
            uintx2 pk;
            pk[0] = pkbf2(p0, p1);
            pk[1] = pkbf2(p2, p3);
            *(uintx2*)&QPs[(w * 16 + lm) * LD + j * 16 + quad * 4] = pk;
        }

        #pragma unroll
        for (int kk = 0; kk < 2; ++kk) {
            bf16x8 pf = *(const bf16x8*)&QPs[(w * 16 + lm) * LD + kk * 32 + quad * 8];
            #pragma unroll
            for (int j = 0; j < 4; ++j) {
                bf16x8 vf = *(const bf16x8*)&Vs[(j * 16 + lm) * LD + kk * 32 + quad * 8];
                o[j] = __builtin_amdgcn_mfma_f32_16x16x32_bf16(pf, vf, o[j], 0, 0, 0);
            }
            l_acc = __builtin_amdgcn_mfma_f32_16x16x32_bf16(pf, ones, l_acc, 0, 0, 0);
        }
    }

    {   // peeled diagonal step (kt == qt), causal mask
        __syncthreads();
        *(ushortx8*)&Ks[r0 * LD + pc] = kreg0;
        *(ushortx8*)&Ks[r1 * LD + pc] = kreg1;
        *(ushortx8*)&Vs[r0 * LD + pc] = vreg0;
        *(ushortx8*)&Vs[r1 * LD + pc] = vreg1;
        __syncthreads();

        floatx4 sa[4] = {};
        #pragma unroll
        for (int kk = 0; kk < 2; ++kk)
            #pragma unroll
            for (int j = 0; j < 4; ++j) {
                bf16x8 kf = *(const bf16x8*)&Ks[(j * 16 + lm) * LD + kk * 32 + quad * 8];
                sa[j] = __builtin_amdgcn_mfma_f32_16x16x32_bf16(kf, qf[kk], sa[j], 0, 0, 0);
            }

        #pragma unroll
        for (int j = 0; j < 4; ++j) {
            int kb = q0 + j * 16 + quad * 4;
            float p0 = (kb + 0 > qrow) ? 0.0f : exp2f(sa[j][0] * c1 - c2);
            float p1 = (kb + 1 > qrow) ? 0.0f : exp2f(sa[j][1] * c1 - c2);
            float p2 = (kb + 2 > qrow) ? 0.0f : exp2f(sa[j][2] * c1 - c2);
            float p3 = (kb + 3 > qrow) ? 0.0f : exp2f(sa[j][3] * c1 - c2);
            uintx2 pk;
            pk[0] = pkbf2(p0, p1);
            pk[1] = pkbf2(p2, p3);
            *(uintx2*)&QPs[(w * 16 + lm) * LD + j * 16 + quad * 4] = pk;
        }

        #pragma unroll
        for (int kk = 0; kk < 2; ++kk) {
            bf16x8 pf = *(const bf16x8*)&QPs[(w * 16 + lm) * LD + kk * 32 + quad * 8];
            #pragma unroll
            for (int j = 0; j < 4; ++j) {
                bf16x8 vf = *(const bf16x8*)&Vs[(j * 16 + lm) * LD + kk * 32 + quad * 8];
                o[j] = __builtin_amdgcn_mfma_f32_16x16x32_bf16(pf, vf, o[j], 0, 0, 0);
            }
            l_acc = __builtin_amdgcn_mfma_f32_16x16x32_bf16(pf, ones, l_acc, 0, 0, 0);
        }
    }

    float rinv[4];
    #pragma unroll
    for (int r = 0; r < 4; ++r) rinv[r] = 1.0f / l_acc[r];

    #pragma unroll
    for (int j = 0; j < 4; ++j) {
        int colg = h * 64 + j * 16 + lm;
        #pragma unroll
        for (int r = 0; r < 4; ++r) {
            int rowg = q0 + w * 16 + quad * 4 + r;
            Y[((size_t)(b * 2048 + rowg)) * 1024 + colg] = f2bf(o[j][r] * rinv[r]);
        }
    }
}

// ---------------------------------------------------------------------------
extern "C" void kernel_launch(void* const* d_in, const int* in_sizes, int n_in,
                              void* d_out, int out_size, void* d_ws, size_t ws_size,
                              hipStream_t stream)
{
    const float* x      = (const float*)d_in[0];   // [2,2048,1024] fp32
    const float* w_attn = (const float*)d_in[1];   // [3072,1024] fp32
    const float* w_proj = (const float*)d_in[2];   // [1024,1024] fp32
    float* out = (float*)d_out;                    // [2,2048,1024] fp32

    // ws: qk 16.8MB | Vt 8.4MB | y 8.4MB | wpb 2.1MB  (35.7 MB total)
    unsigned short* qkbuf = (unsigned short*)d_ws;
    unsigned short* Vtb   = qkbuf + (size_t)4096 * 2048;
    unsigned short* y     = Vtb   + (size_t)32 * 64 * 2048;
    unsigned short* wpb   = y     + (size_t)4096 * 1024;
    // d_out doubles as pre-cast scratch for xb/wab (dead before proj writes):
    unsigned short* xb  = (unsigned short*)d_out;             // 8.4MB
    unsigned short* wab = xb + (size_t)4096 * 1024;           // 6.3MB

    dim3 blk(256);
    cast_inputs<<<dim3(1024), blk, 0, stream>>>(x, w_attn, w_proj, xb, wab, wpb);
    // qkv GEMM + fused rmsnorm/rope (q,k) + transposed V
    gemm_bt<true, 128, 32>
        <<<dim3(24, 32), blk, 0, stream>>>(xb, wab, qkbuf, nullptr, Vtb, 4096, 3072, 1024);
    attention<<<dim3(32, 32), blk, 0, stream>>>(qkbuf, Vtb, y);
    gemm_bt<false, 64, 64>
        <<<dim3(16, 32), blk, 0, stream>>>(y, wpb, nullptr, out, nullptr, 4096, 1024, 1024);
}

// Round 10
// 180.364 us; speedup vs baseline: 3.9904x; 1.0205x over previous
//
#include <hip/hip_runtime.h>
#include <cstdint>
#include <cstddef>

// CausalSelfAttention MI355X (gfx950). fp32 I/O, bf16 MFMA compute, fp32 accum.
// B=2, T=2048, C=1024, H=16, Dh=64.
// [cast f32->bf16] -> [gemm qkv (global_load_lds) with FUSED rmsnorm+rope
// epilogue on q/k and transposed-packed V stores] -> [flash attention: S^T,
// static-max softmax, peeled diagonal, MFMA row-sums, DOUBLE-BUFFERED K/V LDS
// with ONE barrier/step (statically-unrolled buffer parity)] -> [gemm proj].
// Round-6 lesson: NEVER dynamically index register arrays. All static here.

typedef short bf16x8 __attribute__((ext_vector_type(8)));
typedef float floatx4 __attribute__((ext_vector_type(4)));
typedef unsigned short ushortx8 __attribute__((ext_vector_type(8)));
typedef unsigned short ushortx4 __attribute__((ext_vector_type(4)));
typedef unsigned int uintx2 __attribute__((ext_vector_type(2)));

#define DEVI __device__ __forceinline__

DEVI float bf2f(unsigned short u) {
    unsigned int x = ((unsigned int)u) << 16;
    return __builtin_bit_cast(float, x);
}
DEVI unsigned short f2bf(float f) {
    unsigned int u = __builtin_bit_cast(unsigned int, f);
    u += 0x7fffu + ((u >> 16) & 1u);   // RNE; finite values only
    return (unsigned short)(u >> 16);
}
// pack 2 fp32 -> 2 bf16 in one dword (round-half-up; inputs >= 0 here)
DEVI unsigned int pkbf2(float a, float b) {
    unsigned int ua = __builtin_bit_cast(unsigned int, a) + 0x8000u;
    unsigned int ub = __builtin_bit_cast(unsigned int, b) + 0x8000u;
    return __builtin_amdgcn_perm(ub, ua, 0x07060302);
}

// async global->LDS, 16B per lane; LDS dest = wave-uniform base + lane*16.
DEVI void glds16(const unsigned short* g, unsigned short* l) {
    __builtin_amdgcn_global_load_lds(
        (const __attribute__((address_space(1))) unsigned int*)g,
        (__attribute__((address_space(3))) unsigned int*)l, 16, 0, 0);
}

DEVI void cast8(unsigned short* dst, const float* src) {
    floatx4 a = *(const floatx4*)src;
    floatx4 b = *(const floatx4*)(src + 4);
    ushortx8 o;
    o[0] = f2bf(a[0]); o[1] = f2bf(a[1]); o[2] = f2bf(a[2]); o[3] = f2bf(a[3]);
    o[4] = f2bf(b[0]); o[5] = f2bf(b[1]); o[6] = f2bf(b[2]); o[7] = f2bf(b[3]);
    *(ushortx8*)dst = o;
}

// ---------------------------------------------------------------------------
__global__ __launch_bounds__(256)
void cast_inputs(const float* __restrict__ x, const float* __restrict__ wa,
                 const float* __restrict__ wp,
                 unsigned short* __restrict__ xb, unsigned short* __restrict__ wab,
                 unsigned short* __restrict__ wpb)
{
    size_t g = (size_t)blockIdx.x * 256 + threadIdx.x;
    size_t stride = (size_t)gridDim.x * 256;
    for (size_t i = g; i < (4194304 / 8); i += stride) cast8(xb  + i * 8, x  + i * 8);
    for (size_t i = g; i < (3145728 / 8); i += stride) cast8(wab + i * 8, wa + i * 8);
    for (size_t i = g; i < (1048576 / 8); i += stride) cast8(wpb + i * 8, wp + i * 8);
}

// ---------------------------------------------------------------------------
// C[M,N] = A[M,K] @ B[N,K]^T, bf16 in, fp32 accum. m97 structure: 128xBN
// tile, BK in {32,64}, global_load_lds width=16 into UNPADDED LDS.
// QKV_SPLIT epilogue: q/k get fused RMSNorm+RoPE; V transposed+packed.
// ---------------------------------------------------------------------------
template <bool QKV_SPLIT, int BN, int BK>
__global__ __launch_bounds__(256)
void gemm_bt(const unsigned short* __restrict__ A, const unsigned short* __restrict__ B,
             unsigned short* __restrict__ Cqk, float* __restrict__ Cf,
             unsigned short* __restrict__ Vt, int M, int N, int K)
{
    constexpr int WCOLS = (BN == 128) ? 2 : 1;
    constexpr int WROWS = 4 / WCOLS;
    constexpr int MI    = 128 / (16 * WROWS);   // 4 (BN=128) or 2 (BN=64)
    constexpr int LPR   = BK / 8;               // lanes per LDS row (16B each)
    constexpr int RPI   = 64 / LPR;             // rows covered per glds16

    __shared__ __align__(16) unsigned short As[128 * BK];
    __shared__ __align__(16) unsigned short Bs[BN * BK];

    const int tid  = threadIdx.x;
    const int lane = tid & 63;
    const int w    = tid >> 6;
    const int wm   = w / WCOLS, wn = w % WCOLS;
    const int quad = lane >> 4;
    const int lm   = lane & 15;
    const int m0 = blockIdx.y * 128;
    const int n0 = blockIdx.x * BN;
    const int sr = lane / LPR;
    const int sc = (lane % LPR) * 8;

    floatx4 acc[MI][4] = {};

    for (int k0 = 0; k0 < K; k0 += BK) {
        __syncthreads();
        #pragma unroll
        for (int i = 0; i < 32 / RPI; ++i) {
            int r = w * 32 + i * RPI;
            glds16(&A[(size_t)(m0 + r + sr) * K + k0 + sc], &As[r * BK]);
        }
        #pragma unroll
        for (int i = 0; i < (BN / 4) / RPI; ++i) {
            int r = w * (BN / 4) + i * RPI;
            glds16(&B[(size_t)(n0 + r + sr) * K + k0 + sc], &Bs[r * BK]);
        }
        __syncthreads();

        #pragma unroll
        for (int kk = 0; kk < BK / 32; ++kk) {
            bf16x8 a[MI];
            #pragma unroll
            for (int i = 0; i < MI; ++i)
                a[i] = *(const bf16x8*)&As[(wm * (16 * MI) + i * 16 + lm) * BK + kk * 32 + quad * 8];
            #pragma unroll
            for (int j = 0; j < 4; ++j) {
                bf16x8 b = *(const bf16x8*)&Bs[(wn * 64 + j * 16 + lm) * BK + kk * 32 + quad * 8];
                #pragma unroll
                for (int i = 0; i < MI; ++i)
                    acc[i][j] = __builtin_amdgcn_mfma_f32_16x16x32_bf16(a[i], b, acc[i][j], 0, 0, 0);
            }
        }
    }

    if constexpr (QKV_SPLIT) {
        const bool is_v = (n0 + wn * 64) >= 2048;   // wave-uniform
        if (!is_v) {
            // ---- fused RMSNorm + RoPE on q/k ----
            float rn[MI][4];
            #pragma unroll
            for (int i = 0; i < MI; ++i)
                #pragma unroll
                for (int r = 0; r < 4; ++r) {
                    float s = 0.0f;
                    #pragma unroll
                    for (int j = 0; j < 4; ++j) s += acc[i][j][r] * acc[i][j][r];
                    s += __shfl_xor(s, 1, 64);
                    s += __shfl_xor(s, 2, 64);
                    s += __shfl_xor(s, 4, 64);
                    s += __shfl_xor(s, 8, 64);
                    rn[i][r] = rsqrtf(s * (1.0f / 64.0f) + 1.1920929e-07f);
                }
            float invf[4];
            #pragma unroll
            for (int j = 0; j < 4; ++j) {
                int d = j * 16 + lm;
                invf[j] = __expf(-(float)(d & 31) * 0.28782313662425572f); // ln(1e4)/32
            }
            #pragma unroll
            for (int i = 0; i < MI; ++i)
                #pragma unroll
                for (int r = 0; r < 4; ++r) {
                    int row = m0 + wm * (16 * MI) + i * 16 + quad * 4 + r;
                    float t = (float)(row & 2047);
                    float g = rn[i][r];
                    #pragma unroll
                    for (int j = 0; j < 4; ++j) {
                        int d = j * 16 + lm;
                        float sn, cs;
                        __sincosf(t * invf[j], &sn, &cs);
                        float v  = acc[i][j][r] * g;
                        float vp = acc[i][j ^ 2][r] * g;          // partner d^32
                        float sgn = (d < 32) ? -1.0f : 1.0f;      // (-x2, x1)
                        Cqk[(size_t)row * 2048 + (n0 + wn * 64 + d)] =
                            f2bf(v * cs + sgn * vp * sn);
                    }
                }
        } else {
            // ---- V: transposed, b64-packed ----
            #pragma unroll
            for (int i = 0; i < MI; ++i)
                #pragma unroll
                for (int j = 0; j < 4; ++j) {
                    int col  = n0 + wn * 64 + j * 16 + lm;
                    int row0 = m0 + wm * (16 * MI) + i * 16 + quad * 4;
                    int bq = row0 >> 11, t0 = row0 & 2047;
                    ushortx4 pk;
                    #pragma unroll
                    for (int r = 0; r < 4; ++r) pk[r] = f2bf(acc[i][j][r]);
                    *(ushortx4*)&Vt[((size_t)(bq * 1024 + (col - 2048))) * 2048 + t0] = pk;
                }
        }
    } else {
        #pragma unroll
        for (int i = 0; i < MI; ++i)
            #pragma unroll
            for (int j = 0; j < 4; ++j) {
                int col  = n0 + wn * 64 + j * 16 + lm;
                int row0 = m0 + wm * (16 * MI) + i * 16 + quad * 4;
                #pragma unroll
                for (int r = 0; r < 4; ++r)
                    Cf[(size_t)(row0 + r) * N + col] = acc[i][j][r];
            }
    }
}

// ---------------------------------------------------------------------------
// Flash attention. Double-buffered K/V LDS, ONE __syncthreads per key-step,
// buffer parity statically unrolled (pair loop + remainder — zero dynamic
// indexing). Peeled diagonal step (masked, no staging, no trailing barrier).
// S^T via mfma(A=K, B=Q); P packed b64 to own LDS strip; row-sums via
// mfma(P, ones) in o's D-layout.
// ---------------------------------------------------------------------------
#define ATTN_STEP(KSc, VSc, KSn, VSn, KT, DG, LAST)                            \
  do {                                                                         \
    if (!(LAST)) {                                                             \
      *(ushortx8*)&(KSn)[r0 * LD + pc] = kreg0;                                \
      *(ushortx8*)&(KSn)[r1 * LD + pc] = kreg1;                                \
      *(ushortx8*)&(VSn)[r0 * LD + pc] = vreg0;                                \
      *(ushortx8*)&(VSn)[r1 * LD + pc] = vreg1;                                \
      if ((KT) + 2 <= qt) {                                                    \
        kreg0 = *(const ushortx8*)kp0; kreg1 = *(const ushortx8*)kp1;          \
        vreg0 = *(const ushortx8*)vp0; vreg1 = *(const ushortx8*)vp1;          \
        kp0 += (size_t)64 * 2048; kp1 += (size_t)64 * 2048;                    \
        vp0 += 64; vp1 += 64;                                                  \
      }                                                                        \
    }                                                                          \
    floatx4 sa[4] = {};                                                        \
    _Pragma("unroll")                                                          \
    for (int kk = 0; kk < 2; ++kk)                                             \
      _Pragma("unroll")                                                        \
      for (int j = 0; j < 4; ++j) {                                            \
        bf16x8 kf = *(const bf16x8*)&(KSc)[(j * 16 + lm) * LD + kk * 32 + quad * 8]; \
        sa[j] = __builtin_amdgcn_mfma_f32_16x16x32_bf16(kf, qf[kk], sa[j], 0, 0, 0); \
      }                                                                        \
    _Pragma("unroll")                                                          \
    for (int j = 0; j < 4; ++j) {                                              \
      float p0 = exp2f(sa[j][0] * c1 - c2);                                    \
      float p1 = exp2f(sa[j][1] * c1 - c2);                                    \
      float p2 = exp2f(sa[j][2] * c1 - c2);                                    \
      float p3 = exp2f(sa[j][3] * c1 - c2);                                    \
      if (DG) {                                                                \
        int kb = (KT) * 64 + j * 16 + quad * 4;                                \
        if (kb + 0 > qrow) p0 = 0.0f;                                          \
        if (kb + 1 > qrow) p1 = 0.0f;                                          \
        if (kb + 2 > qrow) p2 = 0.0f;                                          \
        if (kb + 3 > qrow) p3 = 0.0f;                                          \
      }                                                                        \
      uintx2 pk;                                                               \
      pk[0] = pkbf2(p0, p1);                                                   \
      pk[1] = pkbf2(p2, p3);                                                   \
      *(uintx2*)&QPs[(w * 16 + lm) * LD + j * 16 + quad * 4] = pk;             \
    }                                                                          \
    _Pragma("unroll")                                                          \
    for (int kk = 0; kk < 2; ++kk) {                                           \
      bf16x8 pf = *(const bf16x8*)&QPs[(w * 16 + lm) * LD + kk * 32 + quad * 8]; \
      _Pragma("unroll")                                                        \
      for (int j = 0; j < 4; ++j) {                                            \
        bf16x8 vf = *(const bf16x8*)&(VSc)[(j * 16 + lm) * LD + kk * 32 + quad * 8]; \
        o[j] = __builtin_amdgcn_mfma_f32_16x16x32_bf16(pf, vf, o[j], 0, 0, 0); \
      }                                                                        \
      l_acc = __builtin_amdgcn_mfma_f32_16x16x32_bf16(pf, ones, l_acc, 0, 0, 0); \
    }                                                                          \
    if (!(LAST)) __syncthreads();                                              \
  } while (0)

__global__ __launch_bounds__(256)
void attention(const unsigned short* __restrict__ qk,
               const unsigned short* __restrict__ Vt,
               unsigned short* __restrict__ Y)
{
    constexpr int LD = 72;
    __shared__ __align__(16) unsigned short QPs[64 * LD];  // Q stage, then P
    __shared__ __align__(16) unsigned short Ks0[64 * LD];
    __shared__ __align__(16) unsigned short Ks1[64 * LD];
    __shared__ __align__(16) unsigned short Vs0[64 * LD];
    __shared__ __align__(16) unsigned short Vs1[64 * LD];

    const int tid  = threadIdx.x;
    const int lane = tid & 63;
    const int w    = tid >> 6;
    const int quad = lane >> 4;
    const int lm   = lane & 15;

    const int bh = blockIdx.x;
    const int qt = 31 - blockIdx.y;      // longest first
    const int b  = bh >> 4, h = bh & 15;
    const int q0 = qt * 64;
    const int qrow = q0 + w * 16 + lm;   // this lane's q-row (S^T layout)

    const int r0 = tid >> 3, r1 = r0 + 32, pc = (tid & 7) * 8;
    const unsigned short* kp0 = qk + (size_t)b * 2048 * 2048 + 1024 + h * 64
                              + (size_t)r0 * 2048 + pc;
    const unsigned short* kp1 = kp0 + (size_t)32 * 2048;
    const unsigned short* vp0 = Vt + (size_t)bh * 64 * 2048 + (size_t)r0 * 2048 + pc;
    const unsigned short* vp1 = vp0 + (size_t)32 * 2048;

    // stage Q tile
    #pragma unroll
    for (int i = 0; i < 2; ++i) {
        int c = i * 256 + tid, row = c >> 3, col = (c & 7) * 8;
        *(ushortx8*)&QPs[row * LD + col] =
            *(const ushortx8*)&qk[((size_t)(b * 2048 + q0 + row)) * 2048 + h * 64 + col];
    }

    // tile 0 -> buf0 directly; prefetch tile 1 into regs
    ushortx8 kreg0 = *(const ushortx8*)kp0, kreg1 = *(const ushortx8*)kp1;
    ushortx8 vreg0 = *(const ushortx8*)vp0, vreg1 = *(const ushortx8*)vp1;
    kp0 += (size_t)64 * 2048; kp1 += (size_t)64 * 2048;
    vp0 += 64; vp1 += 64;
    *(ushortx8*)&Ks0[r0 * LD + pc] = kreg0;
    *(ushortx8*)&Ks0[r1 * LD + pc] = kreg1;
    *(ushortx8*)&Vs0[r0 * LD + pc] = vreg0;
    *(ushortx8*)&Vs0[r1 * LD + pc] = vreg1;
    if (qt >= 1) {
        kreg0 = *(const ushortx8*)kp0; kreg1 = *(const ushortx8*)kp1;
        vreg0 = *(const ushortx8*)vp0; vreg1 = *(const ushortx8*)vp1;
        kp0 += (size_t)64 * 2048; kp1 += (size_t)64 * 2048;
        vp0 += 64; vp1 += 64;
    }
    __syncthreads();                     // Q + tile0 visible

    bf16x8 qf[2];
    #pragma unroll
    for (int kk = 0; kk < 2; ++kk)
        qf[kk] = *(const bf16x8*)&QPs[(w * 16 + lm) * LD + kk * 32 + quad * 8];

    bf16x8 ones;
    #pragma unroll
    for (int i = 0; i < 8; ++i) ones[i] = (short)0x3F80;   // bf16 1.0

    floatx4 o[4] = {};
    floatx4 l_acc = {};                  // row-sums, same D-layout rows as o
    const float c1 = 0.125f * 1.44269504f;   // scale * log2(e)
    const float c2 = 8.0f   * 1.44269504f;   // static max 8

    // mask-free steps in pairs (buffer parity static: even kt -> buf0)
    int kt = 0;
    for (; kt + 1 < qt; kt += 2) {
        ATTN_STEP(Ks0, Vs0, Ks1, Vs1, kt,     false, false);
        ATTN_STEP(Ks1, Vs1, Ks0, Vs0, kt + 1, false, false);
    }
    if (kt < qt) {                       // kt even here; one more mask-free step
        ATTN_STEP(Ks0, Vs0, Ks1, Vs1, kt, false, false);
        // diagonal lives in buf1 (qt odd)
        ATTN_STEP(Ks1, Vs1, Ks0, Vs0, qt, true, true);
    } else {                             // kt == qt (qt even): diagonal in buf0
        ATTN_STEP(Ks0, Vs0, Ks1, Vs1, qt, true, true);
    }

    float rinv[4];
    #pragma unroll
    for (int r = 0; r < 4; ++r) rinv[r] = 1.0f / l_acc[r];

    #pragma unroll
    for (int j = 0; j < 4; ++j) {
        int colg = h * 64 + j * 16 + lm;
        #pragma unroll
        for (int r = 0; r < 4; ++r) {
            int rowg = q0 + w * 16 + quad * 4 + r;
            Y[((size_t)(b * 2048 + rowg)) * 1024 + colg] = f2bf(o[j][r] * rinv[r]);
        }
    }
}

// ---------------------------------------------------------------------------
extern "C" void kernel_launch(void* const* d_in, const int* in_sizes, int n_in,
                              void* d_out, int out_size, void* d_ws, size_t ws_size,
                              hipStream_t stream)
{
    const float* x      = (const float*)d_in[0];   // [2,2048,1024] fp32
    const float* w_attn = (const float*)d_in[1];   // [3072,1024] fp32
    const float* w_proj = (const float*)d_in[2];   // [1024,1024] fp32
    float* out = (float*)d_out;                    // [2,2048,1024] fp32

    // ws: qk 16.8MB | Vt 8.4MB | y 8.4MB | wpb 2.1MB  (35.7 MB total)
    unsigned short* qkbuf = (unsigned short*)d_ws;
    unsigned short* Vtb   = qkbuf + (size_t)4096 * 2048;
    unsigned short* y     = Vtb   + (size_t)32 * 64 * 2048;
    unsigned short* wpb   = y     + (size_t)4096 * 1024;
    // d_out doubles as pre-cast scratch for xb/wab (dead before proj writes):
    unsigned short* xb  = (unsigned short*)d_out;             // 8.4MB
    unsigned short* wab = xb + (size_t)4096 * 1024;           // 6.3MB

    dim3 blk(256);
    cast_inputs<<<dim3(1024), blk, 0, stream>>>(x, w_attn, w_proj, xb, wab, wpb);
    // qkv GEMM + fused rmsnorm/rope (q,k) + transposed V
    gemm_bt<true, 128, 32>
        <<<dim3(24, 32), blk, 0, stream>>>(xb, wab, qkbuf, nullptr, Vtb, 4096, 3072, 1024);
    attention<<<dim3(32, 32), blk, 0, stream>>>(qkbuf, Vtb, y);
    gemm_bt<false, 64, 64>
        <<<dim3(16, 32), blk, 0, stream>>>(y, wpb, nullptr, out, nullptr, 4096, 1024, 1024);
}